// Round 11
// baseline (149.255 us; speedup 1.0000x reference)
//
#include <hip/hip_runtime.h>
#include <hip/hip_bf16.h>

// ConvSelfAttn: B=8, N=4096, C=64, d=8. FP32 I/O.
// R11: mf folded into S-MFMA via 9th K-channel (quad2 ones in Kf, -mf in bq)
// -> no per-element subtract. K pair-interleaved b128 loads (2/iter not 4).
// Proj: grid 256, 2 pixel-groups/block (weight staging halved), knorm fused
// via atomicMax. Static-max softmax (Cauchy-Schwarz bound) as R10.

#define BB 8
#define NN 4096
#define CC 64
#define PSTRIDE 72
#define LOG2E 1.44269504088896f

typedef _Float16 f16;
typedef _Float16 half8 __attribute__((ext_vector_type(8)));
typedef _Float16 half4 __attribute__((ext_vector_type(4)));
typedef __fp16 fp16x2 __attribute__((ext_vector_type(2)));
typedef float floatx4 __attribute__((ext_vector_type(4)));

static __device__ inline half4 pack4(float a, float b, float c, float d) {
    fp16x2 lo = __builtin_amdgcn_cvt_pkrtz(a, b);
    fp16x2 hi = __builtin_amdgcn_cvt_pkrtz(c, d);
    unsigned int lou = __builtin_bit_cast(unsigned int, lo);
    unsigned int hiu = __builtin_bit_cast(unsigned int, hi);
    unsigned long long packed = (unsigned long long)lou | ((unsigned long long)hiu << 32);
    return __builtin_bit_cast(half4, packed);
}

// ws layouts (halfs):
//   Qh [B*N][8]                          Q pre-scaled by log2e
//   Kf [B][128 pair][64 lane][8]         pair-interleaved A-frags: halfs 0-3 =
//                                        even 16-key tile, 4-7 = odd tile;
//                                        quad2 = {1,0,0,0} (mf channel), quad3 = 0
//   Vf [B][128 kb32][4 ct][64 lane][8]   A-frags for 16x16x32 PV
//   qn2 [B*N] f32, Mk2u [B] u32 (atomicMax bits of ||k||^2 max)

// ---------------- fused projection + fragment repack + norm-max ----------------
// grid 256 x 256: block = 128 pixels of one batch, 2 pixel-groups of 64.
__global__ __launch_bounds__(256) void proj_all_kernel(
    const float* __restrict__ x,
    const float* __restrict__ wq, const float* __restrict__ bq,
    const float* __restrict__ wk, const float* __restrict__ bk,
    const float* __restrict__ wv, const float* __restrict__ bv,
    f16* __restrict__ Qh, f16* __restrict__ Kf, f16* __restrict__ Vf,
    float* __restrict__ qn2, unsigned int* __restrict__ Mk2u)
{
    __shared__ alignas(16) f16 Ws[80][PSTRIDE];  // rows 0-63=V, 64-71=Q, 72-79=K
    __shared__ float Bs[80];
    __shared__ alignas(16) f16 Vs[64][68];
    __shared__ alignas(16) f16 Ks[64][12];
    const int tid = threadIdx.x;

    for (int i = tid; i < 4096; i += 256) {
        int cin = i >> 6, cout = i & 63;
        Ws[cout][cin] = (f16)wv[i];
    }
    for (int i = tid; i < 512; i += 256) {
        int cin = i >> 3, c = i & 7;
        Ws[64 + c][cin] = (f16)(wq[i] * LOG2E);
        Ws[72 + c][cin] = (f16)wk[i];
    }
    if (tid < 80)
        Bs[tid] = (tid < 64) ? bv[tid]
                : (tid < 72 ? bq[tid - 64] * LOG2E : bk[tid - 72]);
    __syncthreads();

    const int wave = tid >> 6, lane = tid & 63;
    const int quad = lane >> 4, n16 = lane & 15;
    const long pbB = (long)blockIdx.x * 128;      // block pixel base
    const int  b   = (int)(pbB >> 12);

    for (int pg = 0; pg < 2; ++pg) {
        const long p0  = pbB + pg * 64 + wave * 16;
        const int  nnb = (int)((pbB + pg * 64) & 4095);

        half8 ax[2];
#pragma unroll
        for (int kh = 0; kh < 2; ++kh) {
            const float* xp = x + (p0 + n16) * 64 + kh * 32 + quad * 8;
            float4 x1 = *(const float4*)xp;
            float4 x2 = *(const float4*)(xp + 4);
            ax[kh][0] = (f16)x1.x; ax[kh][1] = (f16)x1.y;
            ax[kh][2] = (f16)x1.z; ax[kh][3] = (f16)x1.w;
            ax[kh][4] = (f16)x2.x; ax[kh][5] = (f16)x2.y;
            ax[kh][6] = (f16)x2.z; ax[kh][7] = (f16)x2.w;
        }

        float kmax = 0.f;
#pragma unroll
        for (int ct = 0; ct < 5; ++ct) {
            const int cout = (ct < 4) ? ct * 16 + n16 : 64 + n16;
            const float bias = Bs[cout];
            half8 b0 = *(const half8*)(&Ws[cout][quad * 8]);
            half8 b1 = *(const half8*)(&Ws[cout][32 + quad * 8]);
            floatx4 acc = {bias, bias, bias, bias};
            acc = __builtin_amdgcn_mfma_f32_16x16x32_f16(ax[0], b0, acc, 0, 0, 0);
            acc = __builtin_amdgcn_mfma_f32_16x16x32_f16(ax[1], b1, acc, 0, 0, 0);
            if (ct < 4) {
#pragma unroll
                for (int r = 0; r < 4; ++r)
                    Vs[wave * 16 + quad * 4 + r][ct * 16 + n16] = (f16)acc[r];
            } else {
                float n2[4];
#pragma unroll
                for (int r = 0; r < 4; ++r) n2[r] = acc[r] * acc[r];
#pragma unroll
                for (int d = 1; d < 8; d <<= 1)
#pragma unroll
                    for (int r = 0; r < 4; ++r) n2[r] += __shfl_xor(n2[r], d, 64);
                if (n16 == 0) {
#pragma unroll
                    for (int r = 0; r < 4; ++r) qn2[p0 + quad * 4 + r] = n2[r];
                } else if (n16 == 8) {
                    kmax = fmaxf(fmaxf(n2[0], n2[1]), fmaxf(n2[2], n2[3]));
                }
                if (n16 < 8) {
                    f16* dst = Qh + (p0 + quad * 4) * 8 + n16;
#pragma unroll
                    for (int r = 0; r < 4; ++r) dst[r * 8] = (f16)acc[r];
                } else {
#pragma unroll
                    for (int r = 0; r < 4; ++r)
                        Ks[wave * 16 + quad * 4 + r][n16 - 8] = (f16)acc[r];
                }
            }
        }
        // per-batch max ||k||^2 via atomic (lanes n16==8 hold kmax)
        kmax = fmaxf(kmax, __shfl_xor(kmax, 16, 64));
        kmax = fmaxf(kmax, __shfl_xor(kmax, 32, 64));
        if (lane == 8) atomicMax(&Mk2u[b], __float_as_uint(kmax));
        __syncthreads();

        // V fragment stores (2 tiles per wave)
#pragma unroll
        for (int u = 0; u < 2; ++u) {
            const int tt = wave * 2 + u;
            const int kb = tt >> 2, ct = tt & 3;
            half8 v;
#pragma unroll
            for (int j = 0; j < 8; ++j)
                v[j] = Vs[kb * 32 + quad * 8 + j][ct * 16 + n16];
            const size_t kbg = (size_t)b * 128 + (nnb >> 5) + kb;
            *(half8*)(Vf + (kbg * 4 + ct) * 512 + lane * 8) = v;
        }
        // K fragment store, pair-interleaved; all 64 lanes write.
        {
            half4 kv = {0, 0, 0, 0};
            if (quad < 2) {
#pragma unroll
                for (int j = 0; j < 4; ++j)
                    kv[j] = Ks[wave * 16 + n16][quad * 4 + j];
            } else if (quad == 2) {
                kv[0] = (f16)1.f;   // mf channel (k=8)
            }
            const size_t kpg = (size_t)b * 128 + (nnb >> 5) + (wave >> 1);
            *(half4*)(Kf + kpg * 512 + lane * 8 + (wave & 1) * 4) = kv;
        }
        __syncthreads();
    }
}

// ---------------- flash attention, static-max, 32 q/wave, key-split 4 ----------------
// grid B*128 = 1024 x 256 thr; wave = ks (0..3): keys [ks*1024,+1024), 16 iters.
__global__ __launch_bounds__(256, 4) void attn_kernel(
    const f16* __restrict__ Qh, const f16* __restrict__ Kf,
    const f16* __restrict__ Vf,
    const float* __restrict__ qn2, const unsigned int* __restrict__ Mk2u,
    const float* __restrict__ x, const float* __restrict__ gptr,
    float* __restrict__ out)
{
    // union: Pbuf (18.4KB) during K-loop; Obuf (24KB f32) after the barrier.
    __shared__ alignas(16) char smem[24576];
    f16*   Pbuf = (f16*)smem;
    float* Obuf = (float*)smem;
    __shared__ float Ls[4][2][16];

    const int tid  = threadIdx.x;
    const int wave = tid >> 6, lane = tid & 63;
    const int quad = lane >> 4, n16 = lane & 15;
    const int ks = wave;

    const int b  = blockIdx.x & 7;
    const int qt = blockIdx.x >> 3;               // 0..127 (32-query tile)
    const size_t bN = (size_t)b * NN;

    const float mk2 = __uint_as_float(Mk2u[b]);

    // Q B-frags: quads 0-1 = Q data; quad2 = {-mf,0,0,0} (pairs with Kf's ones
    // channel -> S-MFMA emits s - mf directly); quad3 = 0.
    half4 bq4[2];
#pragma unroll
    for (int qt2 = 0; qt2 < 2; ++qt2) {
        const int q = qt * 32 + qt2 * 16 + n16;
        const float mf = __builtin_sqrtf(qn2[bN + q] * mk2) - 12.0f;
        half4 v = {0, 0, 0, 0};
        if (quad < 2)
            v = *(const half4*)(Qh + (bN + q) * 8 + quad * 4);
        else if (quad == 2)
            v[0] = (f16)(-mf);
        bq4[qt2] = v;
    }

    floatx4 oacc[2][4];
#pragma unroll
    for (int qt2 = 0; qt2 < 2; ++qt2)
#pragma unroll
        for (int ct = 0; ct < 4; ++ct) oacc[qt2][ct] = (floatx4){0.f, 0.f, 0.f, 0.f};
    float l_loc[2] = {0.f, 0.f};

    const f16* kfb = Kf + ((size_t)b * 128 + ks * 32) * 512;
    const f16* vfb = Vf + ((size_t)b * 128 + ks * 32) * 2048;
    const floatx4 zero4 = {0.f, 0.f, 0.f, 0.f};
    f16* Pw0 = Pbuf + (wave * 2 + 0) * 16 * PSTRIDE;
    f16* Pw1 = Pbuf + (wave * 2 + 1) * 16 * PSTRIDE;

    for (int it = 0; it < 16; ++it) {
        // K pair loads: one b128 covers two 16-key tiles
        half8 kk0 = *(const half8*)(kfb + (size_t)(it * 2 + 0) * 512 + lane * 8);
        half8 kk1 = *(const half8*)(kfb + (size_t)(it * 2 + 1) * 512 + lane * 8);
        half4 ak[4];
        ak[0] = __builtin_shufflevector(kk0, kk0, 0, 1, 2, 3);
        ak[1] = __builtin_shufflevector(kk0, kk0, 4, 5, 6, 7);
        ak[2] = __builtin_shufflevector(kk1, kk1, 0, 1, 2, 3);
        ak[3] = __builtin_shufflevector(kk1, kk1, 4, 5, 6, 7);

        half8 av0[4];
#pragma unroll
        for (int ct = 0; ct < 4; ++ct)
            av0[ct] = *(const half8*)(vfb + ((size_t)(it * 2) * 4 + ct) * 512 + lane * 8);

        floatx4 sf[4];
#pragma unroll
        for (int t = 0; t < 4; ++t)
            sf[t] = __builtin_amdgcn_mfma_f32_16x16x16f16(ak[t], bq4[0], zero4, 0, 0, 0);

        half8 av1[4];
#pragma unroll
        for (int ct = 0; ct < 4; ++ct)
            av1[ct] = *(const half8*)(vfb + ((size_t)(it * 2 + 1) * 4 + ct) * 512 + lane * 8);

#pragma unroll
        for (int qt2 = 0; qt2 < 2; ++qt2) {
            if (qt2 == 1) {
#pragma unroll
                for (int t = 0; t < 4; ++t)
                    sf[t] = __builtin_amdgcn_mfma_f32_16x16x16f16(ak[t], bq4[1], zero4, 0, 0, 0);
            }
            float rs = 0.f;
#pragma unroll
            for (int t = 0; t < 4; ++t)
#pragma unroll
                for (int r = 0; r < 4; ++r) {
                    float pv = __builtin_exp2f(sf[t][r]);   // mf pre-subtracted
                    sf[t][r] = pv;
                    rs += pv;
                }
            l_loc[qt2] += rs;
            f16* Pw = qt2 ? Pw1 : Pw0;
#pragma unroll
            for (int t = 0; t < 4; ++t) {
                half4 pk = pack4(sf[t][0], sf[t][1], sf[t][2], sf[t][3]);
                *(half4*)(Pw + n16 * PSTRIDE + t * 16 + quad * 4) = pk;
            }
        }
        __asm__ volatile("s_waitcnt lgkmcnt(0)" ::: "memory");

#pragma unroll
        for (int qt2 = 0; qt2 < 2; ++qt2) {
            f16* Pw = qt2 ? Pw1 : Pw0;
            half8 bp0 = *(const half8*)(Pw + n16 * PSTRIDE + quad * 8);
            half8 bp1 = *(const half8*)(Pw + n16 * PSTRIDE + 32 + quad * 8);
#pragma unroll
            for (int ct = 0; ct < 4; ++ct)
                oacc[qt2][ct] = __builtin_amdgcn_mfma_f32_16x16x32_f16(av0[ct], bp0, oacc[qt2][ct], 0, 0, 0);
#pragma unroll
            for (int ct = 0; ct < 4; ++ct)
                oacc[qt2][ct] = __builtin_amdgcn_mfma_f32_16x16x32_f16(av1[ct], bp1, oacc[qt2][ct], 0, 0, 0);
        }
    }

    float l_run[2];
#pragma unroll
    for (int qt2 = 0; qt2 < 2; ++qt2) {
        float l = l_loc[qt2];
        l += __shfl_xor(l, 16, 64);
        l += __shfl_xor(l, 32, 64);
        l_run[qt2] = l;
    }

    __syncthreads();   // all P reads done; reuse Pbuf memory as Obuf (f32)
    if (ks > 0) {
#pragma unroll
        for (int qt2 = 0; qt2 < 2; ++qt2) {
            if (quad == 0) Ls[ks][qt2][n16] = l_run[qt2];
            float* ob = Obuf + (((ks - 1) * 2 + qt2) * 64 + lane) * 16;
#pragma unroll
            for (int ct = 0; ct < 4; ++ct)
                *(floatx4*)(ob + ct * 4) = oacc[qt2][ct];
        }
    }
    __syncthreads();
    if (ks == 0) {
        const float g = gptr[0];
#pragma unroll
        for (int qt2 = 0; qt2 < 2; ++qt2) {
            float l = l_run[qt2];
            float o[16];
#pragma unroll
            for (int ct = 0; ct < 4; ++ct)
#pragma unroll
                for (int r = 0; r < 4; ++r) o[ct * 4 + r] = oacc[qt2][ct][r];
#pragma unroll
            for (int p = 1; p < 4; ++p) {
                l += Ls[p][qt2][n16];
                const float* ob = Obuf + (((p - 1) * 2 + qt2) * 64 + lane) * 16;
#pragma unroll
                for (int i = 0; i < 16; ++i) o[i] += ob[i];
            }
            const float scale = g / l;
            const int q = qt * 32 + qt2 * 16 + n16;
#pragma unroll
            for (int ct = 0; ct < 4; ++ct) {
                const size_t idx = (bN + q) * CC + ct * 16 + quad * 4;
                float4 xr = *(const float4*)(x + idx);
                float4 res;
                res.x = o[ct * 4 + 0] * scale + xr.x;
                res.y = o[ct * 4 + 1] * scale + xr.y;
                res.z = o[ct * 4 + 2] * scale + xr.z;
                res.w = o[ct * 4 + 3] * scale + xr.w;
                *(float4*)(out + idx) = res;
            }
        }
    }
}

extern "C" void kernel_launch(void* const* d_in, const int* in_sizes, int n_in,
                              void* d_out, int out_size, void* d_ws, size_t ws_size,
                              hipStream_t stream) {
    const float* x     = (const float*)d_in[0];
    const float* wq    = (const float*)d_in[1];
    const float* bq    = (const float*)d_in[2];
    const float* wk    = (const float*)d_in[3];
    const float* bk    = (const float*)d_in[4];
    const float* wv    = (const float*)d_in[5];
    const float* bv    = (const float*)d_in[6];
    const float* gamma = (const float*)d_in[7];
    float* out = (float*)d_out;

    // ws: Qh 512KB | Kf 1MB | Vf 4MB | qn2 128KB | Mk2u 32B
    f16* Qh = (f16*)d_ws;
    f16* Kf = Qh + (size_t)BB * NN * 8;
    f16* Vf = Kf + (size_t)BB * 128 * 512;
    float* qn2 = (float*)(Vf + (size_t)BB * 128 * 4 * 512);
    unsigned int* Mk2u = (unsigned int*)(qn2 + (size_t)BB * NN);

    hipMemsetAsync(Mk2u, 0, BB * sizeof(unsigned int), stream);
    proj_all_kernel<<<256, 256, 0, stream>>>(x, wq, bq, wk, bk, wv, bv,
                                             Qh, Kf, Vf, qn2, Mk2u);
    attn_kernel<<<BB * 128, 256, 0, stream>>>(Qh, Kf, Vf, qn2, Mk2u, x, gamma, out);
}

// Round 12
// 148.411 us; speedup vs baseline: 1.0057x; 1.0057x over previous
//
#include <hip/hip_runtime.h>
#include <hip/hip_bf16.h>

// ConvSelfAttn: B=8, N=4096, C=64, d=8. FP32 I/O.
// R12: consolidation. Proj reverted to proven 512-block single-group shape
// (R10) + R11's pair-interleaved Kf & ones-channel; Mk2 via SIGNED atomicMax
// (0xAA poison is negative int -> no memset dispatch). 2 dispatches total.
// Attn = R11 (static-max softmax, mf folded into MFMA) + rs partial tree.

#define BB 8
#define NN 4096
#define CC 64
#define PSTRIDE 72
#define LOG2E 1.44269504088896f

typedef _Float16 f16;
typedef _Float16 half8 __attribute__((ext_vector_type(8)));
typedef _Float16 half4 __attribute__((ext_vector_type(4)));
typedef __fp16 fp16x2 __attribute__((ext_vector_type(2)));
typedef float floatx4 __attribute__((ext_vector_type(4)));

static __device__ inline half4 pack4(float a, float b, float c, float d) {
    fp16x2 lo = __builtin_amdgcn_cvt_pkrtz(a, b);
    fp16x2 hi = __builtin_amdgcn_cvt_pkrtz(c, d);
    unsigned int lou = __builtin_bit_cast(unsigned int, lo);
    unsigned int hiu = __builtin_bit_cast(unsigned int, hi);
    unsigned long long packed = (unsigned long long)lou | ((unsigned long long)hiu << 32);
    return __builtin_bit_cast(half4, packed);
}

// ws layouts (halfs):
//   Qh [B*N][8]                          Q pre-scaled by log2e
//   Kf [B][128 pair][64 lane][8]         pair-interleaved A-frags; halfs 0-3 =
//                                        even 16-key tile, 4-7 = odd; quad2 =
//                                        {1,0,0,0} (mf channel), quad3 = 0
//   Vf [B][128 kb32][4 ct][64 lane][8]   A-frags for 16x16x32 PV
//   qn2 [B*N] f32, Mk2i [B] i32 (atomicMax of float bits; ws-poison negative)

// ---------------- fused projection + fragment repack + norm-max ----------------
// grid 512 x 256 (4 waves x 16 pixels; block = 64 pixels of one batch)
__global__ __launch_bounds__(256) void proj_all_kernel(
    const float* __restrict__ x,
    const float* __restrict__ wq, const float* __restrict__ bq,
    const float* __restrict__ wk, const float* __restrict__ bk,
    const float* __restrict__ wv, const float* __restrict__ bv,
    f16* __restrict__ Qh, f16* __restrict__ Kf, f16* __restrict__ Vf,
    float* __restrict__ qn2, int* __restrict__ Mk2i)
{
    __shared__ alignas(16) f16 Ws[80][PSTRIDE];  // rows 0-63=V, 64-71=Q, 72-79=K
    __shared__ float Bs[80];
    __shared__ alignas(16) f16 Vs[64][68];       // [pixel][ch], pitch 68
    __shared__ alignas(16) f16 Ks[64][12];       // [pixel][ch]
    const int tid = threadIdx.x;

    for (int i = tid; i < 4096; i += 256) {
        int cin = i >> 6, cout = i & 63;
        Ws[cout][cin] = (f16)wv[i];
    }
    for (int i = tid; i < 512; i += 256) {
        int cin = i >> 3, c = i & 7;
        Ws[64 + c][cin] = (f16)(wq[i] * LOG2E);
        Ws[72 + c][cin] = (f16)wk[i];
    }
    if (tid < 80)
        Bs[tid] = (tid < 64) ? bv[tid]
                : (tid < 72 ? bq[tid - 64] * LOG2E : bk[tid - 72]);
    __syncthreads();

    const int wave = tid >> 6, lane = tid & 63;
    const int quad = lane >> 4, n16 = lane & 15;
    const long pb = (long)blockIdx.x * 64;
    const long p0 = pb + wave * 16;
    const int  b   = (int)(pb >> 12);
    const int  nnb = (int)(pb & 4095);

    half8 ax[2];
#pragma unroll
    for (int kh = 0; kh < 2; ++kh) {
        const float* xp = x + (p0 + n16) * 64 + kh * 32 + quad * 8;
        float4 x1 = *(const float4*)xp;
        float4 x2 = *(const float4*)(xp + 4);
        ax[kh][0] = (f16)x1.x; ax[kh][1] = (f16)x1.y;
        ax[kh][2] = (f16)x1.z; ax[kh][3] = (f16)x1.w;
        ax[kh][4] = (f16)x2.x; ax[kh][5] = (f16)x2.y;
        ax[kh][6] = (f16)x2.z; ax[kh][7] = (f16)x2.w;
    }

    float kmax = 0.f;
#pragma unroll
    for (int ct = 0; ct < 5; ++ct) {
        const int cout = (ct < 4) ? ct * 16 + n16 : 64 + n16;
        const float bias = Bs[cout];
        half8 b0 = *(const half8*)(&Ws[cout][quad * 8]);
        half8 b1 = *(const half8*)(&Ws[cout][32 + quad * 8]);
        floatx4 acc = {bias, bias, bias, bias};
        acc = __builtin_amdgcn_mfma_f32_16x16x32_f16(ax[0], b0, acc, 0, 0, 0);
        acc = __builtin_amdgcn_mfma_f32_16x16x32_f16(ax[1], b1, acc, 0, 0, 0);
        if (ct < 4) {
#pragma unroll
            for (int r = 0; r < 4; ++r)
                Vs[wave * 16 + quad * 4 + r][ct * 16 + n16] = (f16)acc[r];
        } else {
            float n2[4];
#pragma unroll
            for (int r = 0; r < 4; ++r) n2[r] = acc[r] * acc[r];
#pragma unroll
            for (int d = 1; d < 8; d <<= 1)
#pragma unroll
                for (int r = 0; r < 4; ++r) n2[r] += __shfl_xor(n2[r], d, 64);
            if (n16 == 0) {
#pragma unroll
                for (int r = 0; r < 4; ++r) qn2[p0 + quad * 4 + r] = n2[r];
            } else if (n16 == 8) {
                kmax = fmaxf(fmaxf(n2[0], n2[1]), fmaxf(n2[2], n2[3]));
            }
            if (n16 < 8) {
                f16* dst = Qh + (p0 + quad * 4) * 8 + n16;
#pragma unroll
                for (int r = 0; r < 4; ++r) dst[r * 8] = (f16)acc[r];
            } else {
#pragma unroll
                for (int r = 0; r < 4; ++r)
                    Ks[wave * 16 + quad * 4 + r][n16 - 8] = (f16)acc[r];
            }
        }
    }
    // per-batch max ||k||^2: signed-int atomicMax (ws poison 0xAA.. is
    // negative as int, any real non-negative norm overrides it -> no init)
    kmax = fmaxf(kmax, __shfl_xor(kmax, 16, 64));
    kmax = fmaxf(kmax, __shfl_xor(kmax, 32, 64));
    if (lane == 8) atomicMax(&Mk2i[b], __float_as_int(kmax));
    __syncthreads();

    // V fragment stores (2 tiles per wave)
#pragma unroll
    for (int u = 0; u < 2; ++u) {
        const int tt = wave * 2 + u;
        const int kb = tt >> 2, ct = tt & 3;
        half8 v;
#pragma unroll
        for (int j = 0; j < 8; ++j)
            v[j] = Vs[kb * 32 + quad * 8 + j][ct * 16 + n16];
        const size_t kbg = (size_t)b * 128 + (nnb >> 5) + kb;
        *(half8*)(Vf + (kbg * 4 + ct) * 512 + lane * 8) = v;
    }
    // K fragment store, pair-interleaved; all 64 lanes write.
    {
        half4 kv = {0, 0, 0, 0};
        if (quad < 2) {
#pragma unroll
            for (int j = 0; j < 4; ++j)
                kv[j] = Ks[wave * 16 + n16][quad * 4 + j];
        } else if (quad == 2) {
            kv[0] = (f16)1.f;   // mf channel (k=8)
        }
        const size_t kpg = (size_t)b * 128 + (nnb >> 5) + (wave >> 1);
        *(half4*)(Kf + kpg * 512 + lane * 8 + (wave & 1) * 4) = kv;
    }
}

// ---------------- flash attention, static-max, 32 q/wave, key-split 4 ----------------
// grid B*128 = 1024 x 256 thr; wave = ks (0..3): keys [ks*1024,+1024), 16 iters.
__global__ __launch_bounds__(256, 4) void attn_kernel(
    const f16* __restrict__ Qh, const f16* __restrict__ Kf,
    const f16* __restrict__ Vf,
    const float* __restrict__ qn2, const int* __restrict__ Mk2i,
    const float* __restrict__ x, const float* __restrict__ gptr,
    float* __restrict__ out)
{
    // union: Pbuf (18.4KB) during K-loop; Obuf (24KB f32) after the barrier.
    __shared__ alignas(16) char smem[24576];
    f16*   Pbuf = (f16*)smem;
    float* Obuf = (float*)smem;
    __shared__ float Ls[4][2][16];

    const int tid  = threadIdx.x;
    const int wave = tid >> 6, lane = tid & 63;
    const int quad = lane >> 4, n16 = lane & 15;
    const int ks = wave;

    const int b  = blockIdx.x & 7;
    const int qt = blockIdx.x >> 3;               // 0..127 (32-query tile)
    const size_t bN = (size_t)b * NN;

    const float mk2 = __int_as_float(Mk2i[b]);

    // Q B-frags: quads 0-1 = Q data; quad2 = {-mf,0,0,0}; quad3 = 0.
    half4 bq4[2];
#pragma unroll
    for (int qt2 = 0; qt2 < 2; ++qt2) {
        const int q = qt * 32 + qt2 * 16 + n16;
        const float mf = __builtin_sqrtf(qn2[bN + q] * mk2) - 12.0f;
        half4 v = {0, 0, 0, 0};
        if (quad < 2)
            v = *(const half4*)(Qh + (bN + q) * 8 + quad * 4);
        else if (quad == 2)
            v[0] = (f16)(-mf);
        bq4[qt2] = v;
    }

    floatx4 oacc[2][4];
#pragma unroll
    for (int qt2 = 0; qt2 < 2; ++qt2)
#pragma unroll
        for (int ct = 0; ct < 4; ++ct) oacc[qt2][ct] = (floatx4){0.f, 0.f, 0.f, 0.f};
    float l_loc[2] = {0.f, 0.f};

    const f16* kfb = Kf + ((size_t)b * 128 + ks * 32) * 512;
    const f16* vfb = Vf + ((size_t)b * 128 + ks * 32) * 2048;
    const floatx4 zero4 = {0.f, 0.f, 0.f, 0.f};
    f16* Pw0 = Pbuf + (wave * 2 + 0) * 16 * PSTRIDE;
    f16* Pw1 = Pbuf + (wave * 2 + 1) * 16 * PSTRIDE;

    for (int it = 0; it < 16; ++it) {
        half8 kk0 = *(const half8*)(kfb + (size_t)(it * 2 + 0) * 512 + lane * 8);
        half8 kk1 = *(const half8*)(kfb + (size_t)(it * 2 + 1) * 512 + lane * 8);
        half4 ak[4];
        ak[0] = __builtin_shufflevector(kk0, kk0, 0, 1, 2, 3);
        ak[1] = __builtin_shufflevector(kk0, kk0, 4, 5, 6, 7);
        ak[2] = __builtin_shufflevector(kk1, kk1, 0, 1, 2, 3);
        ak[3] = __builtin_shufflevector(kk1, kk1, 4, 5, 6, 7);

        half8 av0[4];
#pragma unroll
        for (int ct = 0; ct < 4; ++ct)
            av0[ct] = *(const half8*)(vfb + ((size_t)(it * 2) * 4 + ct) * 512 + lane * 8);

        floatx4 sf[4];
#pragma unroll
        for (int t = 0; t < 4; ++t)
            sf[t] = __builtin_amdgcn_mfma_f32_16x16x16f16(ak[t], bq4[0], zero4, 0, 0, 0);

        half8 av1[4];
#pragma unroll
        for (int ct = 0; ct < 4; ++ct)
            av1[ct] = *(const half8*)(vfb + ((size_t)(it * 2 + 1) * 4 + ct) * 512 + lane * 8);

#pragma unroll
        for (int qt2 = 0; qt2 < 2; ++qt2) {
            if (qt2 == 1) {
#pragma unroll
                for (int t = 0; t < 4; ++t)
                    sf[t] = __builtin_amdgcn_mfma_f32_16x16x16f16(ak[t], bq4[1], zero4, 0, 0, 0);
            }
            float rst[4];
#pragma unroll
            for (int t = 0; t < 4; ++t) {
                float pv0 = __builtin_exp2f(sf[t][0]);
                float pv1 = __builtin_exp2f(sf[t][1]);
                float pv2 = __builtin_exp2f(sf[t][2]);
                float pv3 = __builtin_exp2f(sf[t][3]);
                sf[t][0] = pv0; sf[t][1] = pv1; sf[t][2] = pv2; sf[t][3] = pv3;
                rst[t] = (pv0 + pv1) + (pv2 + pv3);
            }
            l_loc[qt2] += (rst[0] + rst[1]) + (rst[2] + rst[3]);
            f16* Pw = qt2 ? Pw1 : Pw0;
#pragma unroll
            for (int t = 0; t < 4; ++t) {
                half4 pk = pack4(sf[t][0], sf[t][1], sf[t][2], sf[t][3]);
                *(half4*)(Pw + n16 * PSTRIDE + t * 16 + quad * 4) = pk;
            }
        }
        __asm__ volatile("s_waitcnt lgkmcnt(0)" ::: "memory");

#pragma unroll
        for (int qt2 = 0; qt2 < 2; ++qt2) {
            f16* Pw = qt2 ? Pw1 : Pw0;
            half8 bp0 = *(const half8*)(Pw + n16 * PSTRIDE + quad * 8);
            half8 bp1 = *(const half8*)(Pw + n16 * PSTRIDE + 32 + quad * 8);
#pragma unroll
            for (int ct = 0; ct < 4; ++ct)
                oacc[qt2][ct] = __builtin_amdgcn_mfma_f32_16x16x32_f16(av0[ct], bp0, oacc[qt2][ct], 0, 0, 0);
#pragma unroll
            for (int ct = 0; ct < 4; ++ct)
                oacc[qt2][ct] = __builtin_amdgcn_mfma_f32_16x16x32_f16(av1[ct], bp1, oacc[qt2][ct], 0, 0, 0);
        }
    }

    float l_run[2];
#pragma unroll
    for (int qt2 = 0; qt2 < 2; ++qt2) {
        float l = l_loc[qt2];
        l += __shfl_xor(l, 16, 64);
        l += __shfl_xor(l, 32, 64);
        l_run[qt2] = l;
    }

    __syncthreads();   // all P reads done; reuse Pbuf memory as Obuf (f32)
    if (ks > 0) {
#pragma unroll
        for (int qt2 = 0; qt2 < 2; ++qt2) {
            if (quad == 0) Ls[ks][qt2][n16] = l_run[qt2];
            float* ob = Obuf + (((ks - 1) * 2 + qt2) * 64 + lane) * 16;
#pragma unroll
            for (int ct = 0; ct < 4; ++ct)
                *(floatx4*)(ob + ct * 4) = oacc[qt2][ct];
        }
    }
    __syncthreads();
    if (ks == 0) {
        const float g = gptr[0];
#pragma unroll
        for (int qt2 = 0; qt2 < 2; ++qt2) {
            float l = l_run[qt2];
            float o[16];
#pragma unroll
            for (int ct = 0; ct < 4; ++ct)
#pragma unroll
                for (int r = 0; r < 4; ++r) o[ct * 4 + r] = oacc[qt2][ct][r];
#pragma unroll
            for (int p = 1; p < 4; ++p) {
                l += Ls[p][qt2][n16];
                const float* ob = Obuf + (((p - 1) * 2 + qt2) * 64 + lane) * 16;
#pragma unroll
                for (int i = 0; i < 16; ++i) o[i] += ob[i];
            }
            const float scale = g / l;
            const int q = qt * 32 + qt2 * 16 + n16;
#pragma unroll
            for (int ct = 0; ct < 4; ++ct) {
                const size_t idx = (bN + q) * CC + ct * 16 + quad * 4;
                float4 xr = *(const float4*)(x + idx);
                float4 res;
                res.x = o[ct * 4 + 0] * scale + xr.x;
                res.y = o[ct * 4 + 1] * scale + xr.y;
                res.z = o[ct * 4 + 2] * scale + xr.z;
                res.w = o[ct * 4 + 3] * scale + xr.w;
                *(float4*)(out + idx) = res;
            }
        }
    }
}

extern "C" void kernel_launch(void* const* d_in, const int* in_sizes, int n_in,
                              void* d_out, int out_size, void* d_ws, size_t ws_size,
                              hipStream_t stream) {
    const float* x     = (const float*)d_in[0];
    const float* wq    = (const float*)d_in[1];
    const float* bq    = (const float*)d_in[2];
    const float* wk    = (const float*)d_in[3];
    const float* bk    = (const float*)d_in[4];
    const float* wv    = (const float*)d_in[5];
    const float* bv    = (const float*)d_in[6];
    const float* gamma = (const float*)d_in[7];
    float* out = (float*)d_out;

    // ws: Qh 512KB | Kf 1MB | Vf 4MB | qn2 128KB | Mk2i 32B
    f16* Qh = (f16*)d_ws;
    f16* Kf = Qh + (size_t)BB * NN * 8;
    f16* Vf = Kf + (size_t)BB * 128 * 512;
    float* qn2 = (float*)(Vf + (size_t)BB * 128 * 4 * 512);
    int* Mk2i = (int*)(qn2 + (size_t)BB * NN);

    proj_all_kernel<<<512, 256, 0, stream>>>(x, wq, bq, wk, bk, wv, bv,
                                             Qh, Kf, Vf, qn2, Mk2i);
    attn_kernel<<<BB * 128, 256, 0, stream>>>(Qh, Kf, Vf, qn2, Mk2i, x, gamma, out);
}

// Round 13
// 129.662 us; speedup vs baseline: 1.1511x; 1.1446x over previous
//
#include <hip/hip_runtime.h>
#include <hip/hip_bf16.h>

// ConvSelfAttn: B=8, N=4096, C=64, d=8. FP32 I/O.
// R13: (1) proj regression fix — Kf pair tiles stored as full-line 16B/lane
// coalesced writes (no partial-line merge), atomicMax removed (knorm kernel
// back, 3 dispatches, R10's proven-low-overhead config). (2) attn register
// experiment: launch_bounds(256,3) -> ~85-reg cap so av0+av1+K can stay live
// (no load serialization); av1 hoisted next to av0. Static-max softmax as R12.

#define BB 8
#define NN 4096
#define CC 64
#define PSTRIDE 72
#define LOG2E 1.44269504088896f

typedef _Float16 f16;
typedef _Float16 half8 __attribute__((ext_vector_type(8)));
typedef _Float16 half4 __attribute__((ext_vector_type(4)));
typedef __fp16 fp16x2 __attribute__((ext_vector_type(2)));
typedef float floatx4 __attribute__((ext_vector_type(4)));

static __device__ inline half4 pack4(float a, float b, float c, float d) {
    fp16x2 lo = __builtin_amdgcn_cvt_pkrtz(a, b);
    fp16x2 hi = __builtin_amdgcn_cvt_pkrtz(c, d);
    unsigned int lou = __builtin_bit_cast(unsigned int, lo);
    unsigned int hiu = __builtin_bit_cast(unsigned int, hi);
    unsigned long long packed = (unsigned long long)lou | ((unsigned long long)hiu << 32);
    return __builtin_bit_cast(half4, packed);
}

// ws layouts (halfs):
//   Qh [B*N][8]                          Q pre-scaled by log2e
//   Kf [B][128 pair][64 lane][8]         pair-interleaved A-frags; halfs 0-3 =
//                                        even 16-key tile, 4-7 = odd; quad2 =
//                                        {1,0,0,0} (mf channel), quad3 = 0
//   Vf [B][128 kb32][4 ct][64 lane][8]   A-frags for 16x16x32 PV
//   qn2 [B*N] f32 | kn2 [B*N] f32 | Mk2 [B] f32

// ---------------- fused projection + fragment repack + norms ----------------
// grid 512 x 256 (4 waves x 16 pixels; block = 64 pixels of one batch)
__global__ __launch_bounds__(256) void proj_all_kernel(
    const float* __restrict__ x,
    const float* __restrict__ wq, const float* __restrict__ bq,
    const float* __restrict__ wk, const float* __restrict__ bk,
    const float* __restrict__ wv, const float* __restrict__ bv,
    f16* __restrict__ Qh, f16* __restrict__ Kf, f16* __restrict__ Vf,
    float* __restrict__ qn2, float* __restrict__ kn2)
{
    __shared__ alignas(16) f16 Ws[80][PSTRIDE];  // rows 0-63=V, 64-71=Q, 72-79=K
    __shared__ float Bs[80];
    __shared__ alignas(16) f16 Vs[64][68];       // [pixel][ch], pitch 68
    __shared__ alignas(16) f16 Ks[64][12];       // [pixel][ch]
    const int tid = threadIdx.x;

    for (int i = tid; i < 4096; i += 256) {
        int cin = i >> 6, cout = i & 63;
        Ws[cout][cin] = (f16)wv[i];
    }
    for (int i = tid; i < 512; i += 256) {
        int cin = i >> 3, c = i & 7;
        Ws[64 + c][cin] = (f16)(wq[i] * LOG2E);
        Ws[72 + c][cin] = (f16)wk[i];
    }
    if (tid < 80)
        Bs[tid] = (tid < 64) ? bv[tid]
                : (tid < 72 ? bq[tid - 64] * LOG2E : bk[tid - 72]);
    __syncthreads();

    const int wave = tid >> 6, lane = tid & 63;
    const int quad = lane >> 4, n16 = lane & 15;
    const long pb = (long)blockIdx.x * 64;
    const long p0 = pb + wave * 16;
    const int  b   = (int)(pb >> 12);
    const int  nnb = (int)(pb & 4095);

    half8 ax[2];
#pragma unroll
    for (int kh = 0; kh < 2; ++kh) {
        const float* xp = x + (p0 + n16) * 64 + kh * 32 + quad * 8;
        float4 x1 = *(const float4*)xp;
        float4 x2 = *(const float4*)(xp + 4);
        ax[kh][0] = (f16)x1.x; ax[kh][1] = (f16)x1.y;
        ax[kh][2] = (f16)x1.z; ax[kh][3] = (f16)x1.w;
        ax[kh][4] = (f16)x2.x; ax[kh][5] = (f16)x2.y;
        ax[kh][6] = (f16)x2.z; ax[kh][7] = (f16)x2.w;
    }

#pragma unroll
    for (int ct = 0; ct < 5; ++ct) {
        const int cout = (ct < 4) ? ct * 16 + n16 : 64 + n16;
        const float bias = Bs[cout];
        half8 b0 = *(const half8*)(&Ws[cout][quad * 8]);
        half8 b1 = *(const half8*)(&Ws[cout][32 + quad * 8]);
        floatx4 acc = {bias, bias, bias, bias};
        acc = __builtin_amdgcn_mfma_f32_16x16x32_f16(ax[0], b0, acc, 0, 0, 0);
        acc = __builtin_amdgcn_mfma_f32_16x16x32_f16(ax[1], b1, acc, 0, 0, 0);
        if (ct < 4) {
#pragma unroll
            for (int r = 0; r < 4; ++r)
                Vs[wave * 16 + quad * 4 + r][ct * 16 + n16] = (f16)acc[r];
        } else {
            float n2[4];
#pragma unroll
            for (int r = 0; r < 4; ++r) n2[r] = acc[r] * acc[r];
#pragma unroll
            for (int d = 1; d < 8; d <<= 1)
#pragma unroll
                for (int r = 0; r < 4; ++r) n2[r] += __shfl_xor(n2[r], d, 64);
            if (n16 == 0) {
#pragma unroll
                for (int r = 0; r < 4; ++r) qn2[p0 + quad * 4 + r] = n2[r];
            } else if (n16 == 8) {
#pragma unroll
                for (int r = 0; r < 4; ++r) kn2[p0 + quad * 4 + r] = n2[r];
            }
            if (n16 < 8) {
                f16* dst = Qh + (p0 + quad * 4) * 8 + n16;
#pragma unroll
                for (int r = 0; r < 4; ++r) dst[r * 8] = (f16)acc[r];
            } else {
#pragma unroll
                for (int r = 0; r < 4; ++r)
                    Ks[wave * 16 + quad * 4 + r][n16 - 8] = (f16)acc[r];
            }
        }
    }
    __syncthreads();

    // V fragment stores (2 tiles per wave), full 16B/lane
#pragma unroll
    for (int u = 0; u < 2; ++u) {
        const int tt = wave * 2 + u;
        const int kb = tt >> 2, ct = tt & 3;
        half8 v;
#pragma unroll
        for (int j = 0; j < 8; ++j)
            v[j] = Vs[kb * 32 + quad * 8 + j][ct * 16 + n16];
        const size_t kbg = (size_t)b * 128 + (nnb >> 5) + kb;
        *(half8*)(Vf + (kbg * 4 + ct) * 512 + lane * 8) = v;
    }
    // K pair-tile stores: waves 0-1 each store one pair as full 16B/lane lines
    if (wave < 2) {
        half8 kp;
#pragma unroll
        for (int e = 0; e < 2; ++e) {
            const int t = wave * 2 + e;
#pragma unroll
            for (int j = 0; j < 4; ++j) {
                f16 v = (f16)0.f;
                if (quad < 2) v = Ks[t * 16 + n16][quad * 4 + j];
                else if (quad == 2 && j == 0) v = (f16)1.f;  // mf ones channel
                kp[e * 4 + j] = v;
            }
        }
        const size_t kpg = (size_t)b * 128 + (nnb >> 5) + wave;
        *(half8*)(Kf + kpg * 512 + lane * 8) = kp;
    }
}

// ---------------- per-batch max key-norm reduce ----------------
__global__ __launch_bounds__(256) void knorm_max_kernel(
    const float* __restrict__ kn2, float* __restrict__ Mk2)
{
    __shared__ float red[4];
    const int b = blockIdx.x, tid = threadIdx.x;
    float mx = 0.f;
    for (int i = tid; i < NN; i += 256) mx = fmaxf(mx, kn2[(size_t)b * NN + i]);
#pragma unroll
    for (int d = 1; d < 64; d <<= 1) mx = fmaxf(mx, __shfl_xor(mx, d, 64));
    if ((tid & 63) == 0) red[tid >> 6] = mx;
    __syncthreads();
    if (tid == 0) Mk2[b] = fmaxf(fmaxf(red[0], red[1]), fmaxf(red[2], red[3]));
}

// ---------------- flash attention, static-max, 32 q/wave, key-split 4 ----------------
// grid B*128 = 1024 x 256 thr; wave = ks (0..3): keys [ks*1024,+1024), 16 iters.
// launch_bounds(256,3): ~85-reg cap so all K/V loads can stay live per iter.
__global__ __launch_bounds__(256, 3) void attn_kernel(
    const f16* __restrict__ Qh, const f16* __restrict__ Kf,
    const f16* __restrict__ Vf,
    const float* __restrict__ qn2, const float* __restrict__ Mk2,
    const float* __restrict__ x, const float* __restrict__ gptr,
    float* __restrict__ out)
{
    // union: Pbuf (18.4KB) during K-loop; Obuf (24KB f32) after the barrier.
    __shared__ alignas(16) char smem[24576];
    f16*   Pbuf = (f16*)smem;
    float* Obuf = (float*)smem;
    __shared__ float Ls[4][2][16];

    const int tid  = threadIdx.x;
    const int wave = tid >> 6, lane = tid & 63;
    const int quad = lane >> 4, n16 = lane & 15;
    const int ks = wave;

    const int b  = blockIdx.x & 7;
    const int qt = blockIdx.x >> 3;               // 0..127 (32-query tile)
    const size_t bN = (size_t)b * NN;

    const float mk2 = Mk2[b];

    // Q B-frags: quads 0-1 = Q data; quad2 = {-mf,0,0,0}; quad3 = 0.
    half4 bq4[2];
#pragma unroll
    for (int qt2 = 0; qt2 < 2; ++qt2) {
        const int q = qt * 32 + qt2 * 16 + n16;
        const float mf = __builtin_sqrtf(qn2[bN + q] * mk2) - 12.0f;
        half4 v = {0, 0, 0, 0};
        if (quad < 2)
            v = *(const half4*)(Qh + (bN + q) * 8 + quad * 4);
        else if (quad == 2)
            v[0] = (f16)(-mf);
        bq4[qt2] = v;
    }

    floatx4 oacc[2][4];
#pragma unroll
    for (int qt2 = 0; qt2 < 2; ++qt2)
#pragma unroll
        for (int ct = 0; ct < 4; ++ct) oacc[qt2][ct] = (floatx4){0.f, 0.f, 0.f, 0.f};
    float l_loc[2] = {0.f, 0.f};

    const f16* kfb = Kf + ((size_t)b * 128 + ks * 32) * 512;
    const f16* vfb = Vf + ((size_t)b * 128 + ks * 32) * 2048;
    const floatx4 zero4 = {0.f, 0.f, 0.f, 0.f};
    f16* Pw0 = Pbuf + (wave * 2 + 0) * 16 * PSTRIDE;
    f16* Pw1 = Pbuf + (wave * 2 + 1) * 16 * PSTRIDE;

    for (int it = 0; it < 16; ++it) {
        // all global loads issued together (85-reg cap keeps them live)
        half8 kk0 = *(const half8*)(kfb + (size_t)(it * 2 + 0) * 512 + lane * 8);
        half8 kk1 = *(const half8*)(kfb + (size_t)(it * 2 + 1) * 512 + lane * 8);
        half8 av0[4], av1[4];
#pragma unroll
        for (int ct = 0; ct < 4; ++ct)
            av0[ct] = *(const half8*)(vfb + ((size_t)(it * 2) * 4 + ct) * 512 + lane * 8);
#pragma unroll
        for (int ct = 0; ct < 4; ++ct)
            av1[ct] = *(const half8*)(vfb + ((size_t)(it * 2 + 1) * 4 + ct) * 512 + lane * 8);

        half4 ak[4];
        ak[0] = __builtin_shufflevector(kk0, kk0, 0, 1, 2, 3);
        ak[1] = __builtin_shufflevector(kk0, kk0, 4, 5, 6, 7);
        ak[2] = __builtin_shufflevector(kk1, kk1, 0, 1, 2, 3);
        ak[3] = __builtin_shufflevector(kk1, kk1, 4, 5, 6, 7);

        floatx4 sf[4];
#pragma unroll
        for (int t = 0; t < 4; ++t)
            sf[t] = __builtin_amdgcn_mfma_f32_16x16x16f16(ak[t], bq4[0], zero4, 0, 0, 0);

#pragma unroll
        for (int qt2 = 0; qt2 < 2; ++qt2) {
            if (qt2 == 1) {
#pragma unroll
                for (int t = 0; t < 4; ++t)
                    sf[t] = __builtin_amdgcn_mfma_f32_16x16x16f16(ak[t], bq4[1], zero4, 0, 0, 0);
            }
            float rst[4];
#pragma unroll
            for (int t = 0; t < 4; ++t) {
                float pv0 = __builtin_exp2f(sf[t][0]);
                float pv1 = __builtin_exp2f(sf[t][1]);
                float pv2 = __builtin_exp2f(sf[t][2]);
                float pv3 = __builtin_exp2f(sf[t][3]);
                sf[t][0] = pv0; sf[t][1] = pv1; sf[t][2] = pv2; sf[t][3] = pv3;
                rst[t] = (pv0 + pv1) + (pv2 + pv3);
            }
            l_loc[qt2] += (rst[0] + rst[1]) + (rst[2] + rst[3]);
            f16* Pw = qt2 ? Pw1 : Pw0;
#pragma unroll
            for (int t = 0; t < 4; ++t) {
                half4 pk = pack4(sf[t][0], sf[t][1], sf[t][2], sf[t][3]);
                *(half4*)(Pw + n16 * PSTRIDE + t * 16 + quad * 4) = pk;
            }
        }
        __asm__ volatile("s_waitcnt lgkmcnt(0)" ::: "memory");

#pragma unroll
        for (int qt2 = 0; qt2 < 2; ++qt2) {
            f16* Pw = qt2 ? Pw1 : Pw0;
            half8 bp0 = *(const half8*)(Pw + n16 * PSTRIDE + quad * 8);
            half8 bp1 = *(const half8*)(Pw + n16 * PSTRIDE + 32 + quad * 8);
#pragma unroll
            for (int ct = 0; ct < 4; ++ct)
                oacc[qt2][ct] = __builtin_amdgcn_mfma_f32_16x16x32_f16(av0[ct], bp0, oacc[qt2][ct], 0, 0, 0);
#pragma unroll
            for (int ct = 0; ct < 4; ++ct)
                oacc[qt2][ct] = __builtin_amdgcn_mfma_f32_16x16x32_f16(av1[ct], bp1, oacc[qt2][ct], 0, 0, 0);
        }
    }

    float l_run[2];
#pragma unroll
    for (int qt2 = 0; qt2 < 2; ++qt2) {
        float l = l_loc[qt2];
        l += __shfl_xor(l, 16, 64);
        l += __shfl_xor(l, 32, 64);
        l_run[qt2] = l;
    }

    __syncthreads();   // all P reads done; reuse Pbuf memory as Obuf (f32)
    if (ks > 0) {
#pragma unroll
        for (int qt2 = 0; qt2 < 2; ++qt2) {
            if (quad == 0) Ls[ks][qt2][n16] = l_run[qt2];
            float* ob = Obuf + (((ks - 1) * 2 + qt2) * 64 + lane) * 16;
#pragma unroll
            for (int ct = 0; ct < 4; ++ct)
                *(floatx4*)(ob + ct * 4) = oacc[qt2][ct];
        }
    }
    __syncthreads();
    if (ks == 0) {
        const float g = gptr[0];
#pragma unroll
        for (int qt2 = 0; qt2 < 2; ++qt2) {
            float l = l_run[qt2];
            float o[16];
#pragma unroll
            for (int ct = 0; ct < 4; ++ct)
#pragma unroll
                for (int r = 0; r < 4; ++r) o[ct * 4 + r] = oacc[qt2][ct][r];
#pragma unroll
            for (int p = 1; p < 4; ++p) {
                l += Ls[p][qt2][n16];
                const float* ob = Obuf + (((p - 1) * 2 + qt2) * 64 + lane) * 16;
#pragma unroll
                for (int i = 0; i < 16; ++i) o[i] += ob[i];
            }
            const float scale = g / l;
            const int q = qt * 32 + qt2 * 16 + n16;
#pragma unroll
            for (int ct = 0; ct < 4; ++ct) {
                const size_t idx = (bN + q) * CC + ct * 16 + quad * 4;
                float4 xr = *(const float4*)(x + idx);
                float4 res;
                res.x = o[ct * 4 + 0] * scale + xr.x;
                res.y = o[ct * 4 + 1] * scale + xr.y;
                res.z = o[ct * 4 + 2] * scale + xr.z;
                res.w = o[ct * 4 + 3] * scale + xr.w;
                *(float4*)(out + idx) = res;
            }
        }
    }
}

extern "C" void kernel_launch(void* const* d_in, const int* in_sizes, int n_in,
                              void* d_out, int out_size, void* d_ws, size_t ws_size,
                              hipStream_t stream) {
    const float* x     = (const float*)d_in[0];
    const float* wq    = (const float*)d_in[1];
    const float* bq    = (const float*)d_in[2];
    const float* wk    = (const float*)d_in[3];
    const float* bk    = (const float*)d_in[4];
    const float* wv    = (const float*)d_in[5];
    const float* bv    = (const float*)d_in[6];
    const float* gamma = (const float*)d_in[7];
    float* out = (float*)d_out;

    // ws: Qh 512KB | Kf 1MB | Vf 4MB | qn2 128KB | kn2 128KB | Mk2 32B
    f16* Qh = (f16*)d_ws;
    f16* Kf = Qh + (size_t)BB * NN * 8;
    f16* Vf = Kf + (size_t)BB * 128 * 512;
    float* qn2 = (float*)(Vf + (size_t)BB * 128 * 4 * 512);
    float* kn2 = qn2 + (size_t)BB * NN;
    float* Mk2 = kn2 + (size_t)BB * NN;

    proj_all_kernel<<<512, 256, 0, stream>>>(x, wq, bq, wk, bk, wv, bv,
                                             Qh, Kf, Vf, qn2, kn2);
    knorm_max_kernel<<<BB, 256, 0, stream>>>(kn2, Mk2);
    attn_kernel<<<BB * 128, 256, 0, stream>>>(Qh, Kf, Vf, qn2, Mk2, x, gamma, out);
}